// Round 9
// baseline (322.324 us; speedup 1.0000x reference)
//
#include <hip/hip_runtime.h>
#include <math.h>

#define BATCH 2
#define NTOK 4096        // H*W
#define CDIM 256
#define NH 8
#define HD 32
#define MROWS (BATCH * NTOK)   // 8192

typedef __attribute__((ext_vector_type(8))) short bf16x8;
typedef __attribute__((ext_vector_type(4))) float f32x4;
typedef __attribute__((ext_vector_type(4))) unsigned u32x4;

union frag_u { uint4 q; u32x4 u; bf16x8 b; };

__device__ __forceinline__ unsigned short f2bf(float f) {
    union { float f; unsigned u; } x; x.f = f;
    unsigned r = x.u + 0x7FFFu + ((x.u >> 16) & 1u);   // RNE
    return (unsigned short)(r >> 16);
}
__device__ __forceinline__ float bf2f(unsigned short h) {
    union { unsigned u; float f; } x; x.u = ((unsigned)h) << 16; return x.f;
}
__device__ __forceinline__ float exp2_fast(float x) {
    float r;
    asm("v_exp_f32 %0, %1\n\ts_nop 0" : "=v"(r) : "v"(x));   // proven r2-r8
    return r;
}
__device__ __forceinline__ unsigned cvt_pk_bf16(float a, float b) {
    unsigned r;   // lo16 = bf16(a), hi16 = bf16(b), RNE
    asm("v_cvt_pk_bf16_f32 %0, %1, %2" : "=v"(r) : "v"(a), "v"(b));
    return r;
}
// C-frag dword pair (tile 2ks, tile 2ks+1) -> B-frag dword pair (w0, w1); proven r3-r8
__device__ __forceinline__ void permlane_pv(unsigned &a, unsigned &b) {
    asm("s_nop 1\n\t"
        "v_permlane32_swap_b32 %0, %1\n\t"
        "s_nop 1\n\t"
        "v_permlane16_swap_b32 %0, %1" : "+v"(a), "+v"(b));
}

// ---------------- QKV projection GEMM (unchanged, working) ----------------
#define BM 64
#define BN 64
#define BK 64

__global__ __launch_bounds__(256) void qkv_gemm(
    const float* __restrict__ X, const float* __restrict__ W,
    const float* __restrict__ bias,
    unsigned short* __restrict__ Qhi, unsigned short* __restrict__ Qlo,
    unsigned short* __restrict__ Khi, unsigned short* __restrict__ Klo,
    unsigned short* __restrict__ Vhi, unsigned short* __restrict__ Vlo)
{
    __shared__ float As[BK][BM + 4];
    __shared__ float Bs[BK][BN + 4];

    const int tid = threadIdx.x;
    const int tx = tid & 15;
    const int ty = tid >> 4;
    const int row0 = blockIdx.x * BM;
    const int col0 = blockIdx.y * BN;

    float c[4][4] = {};

    for (int k0 = 0; k0 < CDIM; k0 += BK) {
        #pragma unroll
        for (int i = 0; i < 4; ++i) {
            int l = tid + i * 256;
            int r = l >> 4;
            int k4 = (l & 15) << 2;
            float4 v = *(const float4*)&X[(size_t)(row0 + r) * CDIM + k0 + k4];
            As[k4 + 0][r] = v.x; As[k4 + 1][r] = v.y;
            As[k4 + 2][r] = v.z; As[k4 + 3][r] = v.w;
        }
        #pragma unroll
        for (int i = 0; i < 4; ++i) {
            int l = tid + i * 256;
            int r = l >> 4;
            int c4 = (l & 15) << 2;
            *(float4*)&Bs[r][c4] = *(const float4*)&W[(size_t)(k0 + r) * 768 + col0 + c4];
        }
        __syncthreads();

        #pragma unroll 16
        for (int kk = 0; kk < BK; ++kk) {
            float4 a = *(const float4*)&As[kk][ty << 2];
            float4 b = *(const float4*)&Bs[kk][tx << 2];
            float av[4] = {a.x, a.y, a.z, a.w};
            float bv[4] = {b.x, b.y, b.z, b.w};
            #pragma unroll
            for (int i = 0; i < 4; ++i)
                #pragma unroll
                for (int j = 0; j < 4; ++j)
                    c[i][j] = fmaf(av[i], bv[j], c[i][j]);
        }
        __syncthreads();
    }

    const int s = col0 >> 8;            // 0=Q 1=K 2=V
    const int b_ = row0 >> 12;
    const int n0 = (row0 & (NTOK - 1)) + (ty << 2);
    const int gc0 = col0 + (tx << 2);
    const int h  = (gc0 >> 5) & 7;
    const int e0 = gc0 & 31;
    const int bh = b_ * NH + h;
    // scale/sqrt(hd) * log2(e): QK^T lands directly in log2 domain
    const float QSC = (float)(1.4426950408889634 / 5.656854249492381);

    if (s == 0) {
        #pragma unroll
        for (int i = 0; i < 4; ++i) {
            unsigned short hh[4], ll[4];
            #pragma unroll
            for (int j = 0; j < 4; ++j) {
                float v = (c[i][j] + bias[gc0 + j]) * QSC;
                hh[j] = f2bf(v);
                ll[j] = f2bf(v - bf2f(hh[j]));
            }
            size_t idx = ((size_t)bh * NTOK + n0 + i) * HD + e0;
            uint2 hw; hw.x = hh[0] | ((unsigned)hh[1] << 16); hw.y = hh[2] | ((unsigned)hh[3] << 16);
            uint2 lw; lw.x = ll[0] | ((unsigned)ll[1] << 16); lw.y = ll[2] | ((unsigned)ll[3] << 16);
            *(uint2*)&Qhi[idx] = hw;
            *(uint2*)&Qlo[idx] = lw;
        }
    } else if (s == 1) {
        #pragma unroll
        for (int i = 0; i < 4; ++i) {
            unsigned short hh[4], ll[4];
            #pragma unroll
            for (int j = 0; j < 4; ++j) {
                float v = c[i][j] + bias[gc0 + j];
                hh[j] = f2bf(v);
                ll[j] = f2bf(v - bf2f(hh[j]));
            }
            size_t idx = ((size_t)bh * NTOK + n0 + i) * HD + e0;
            uint2 hw; hw.x = hh[0] | ((unsigned)hh[1] << 16); hw.y = hh[2] | ((unsigned)hh[3] << 16);
            uint2 lw; lw.x = ll[0] | ((unsigned)ll[1] << 16); lw.y = ll[2] | ((unsigned)ll[3] << 16);
            *(uint2*)&Khi[idx] = hw;
            *(uint2*)&Klo[idx] = lw;
        }
    } else {
        // V transposed: [bh][e][n]
        #pragma unroll
        for (int j = 0; j < 4; ++j) {
            unsigned short hh[4], ll[4];
            #pragma unroll
            for (int i = 0; i < 4; ++i) {
                float v = c[i][j] + bias[gc0 + j];
                hh[i] = f2bf(v);
                ll[i] = f2bf(v - bf2f(hh[i]));
            }
            size_t idx = ((size_t)bh * HD + e0 + j) * NTOK + n0;
            uint2 hw; hw.x = hh[0] | ((unsigned)hh[1] << 16); hw.y = hh[2] | ((unsigned)hh[3] << 16);
            uint2 lw; lw.x = ll[0] | ((unsigned)ll[1] << 16); lw.y = ll[2] | ((unsigned)ll[3] << 16);
            *(uint2*)&Vhi[idx] = hw;
            *(uint2*)&Vlo[idx] = lw;
        }
    }
}

// ---------------- MFMA flash attention v9: K in LDS, V direct from L2 ----------------
// Block = 4 waves x 16 q-rows; grid = 1024 blocks -> 4 blocks/CU, 16 waves/CU.
// K tile staged in LDS (pitch-44 rows: 16 even bank-starts x 4 lanes = balanced
// 8 dwords/bank, conflict-free). V fragments are per-lane coalesced 16B chunks
// of [bh][e][n] rows, loaded straight from L2 right after the barrier and
// consumed ~600 cycles later (after QK^T + softmax) -- 16 waves/CU hide the
// latency. This halves LDS instructions vs v6 and removes the 8-way V-read
// bank conflict (the 12.6M-cycle counter in r8).
// Math identical to r5-r8: 3-term QK, single-bf16 P via cvt_pk+permlane,
// 2-term PV, exp2 domain.
__global__ __launch_bounds__(256, 3) void attn_v9(
    const unsigned short* __restrict__ Qhi, const unsigned short* __restrict__ Qlo,
    const unsigned short* __restrict__ Khi, const unsigned short* __restrict__ Klo,
    const unsigned short* __restrict__ Vhi, const unsigned short* __restrict__ Vlo,
    float* __restrict__ AO)
{
    __shared__ __align__(16) unsigned short KH[64][44], KL[64][44];   // pitch 88B

    const int tid = threadIdx.x;
    const int w = tid >> 6, lane = tid & 63, lq = lane & 15, g = lane >> 4;
    const int bx = blockIdx.x;
    const int bh = bx & 15, qc = bx >> 4;     // same-head blocks share XCD L2
    const int q0 = qc * 64 + w * 16;
    const int kb = bh * (NTOK * HD);          // fits 32-bit
    const int vb = bh * (HD * NTOK);

    // ---- Q fragment (pre-scaled by scale*log2e) ----
    bf16x8 qh, ql;
    {
        const int qi = kb + (q0 + lq) * HD + g * 8;
        qh = *(const bf16x8*)(Qhi + qi);
        ql = *(const bf16x8*)(Qlo + qi);
    }

    // ---- K staging slot: row 0..63 / 16B chunk ----
    const int kr = tid >> 2, kc = (tid & 3) << 3;
    const int kgbase = kb + kr * HD + kc;

    // prologue: load step-0 K tile into regs
    uint4 sKH = *(const uint4*)(Khi + kgbase);
    uint4 sKL = *(const uint4*)(Klo + kgbase);

    // ---- V fragment bases (per-lane, direct from L2) ----
    int vbase[2][2];
    #pragma unroll
    for (int mt = 0; mt < 2; ++mt)
        #pragma unroll
        for (int ks = 0; ks < 2; ++ks)
            vbase[mt][ks] = vb + (16 * mt + lq) * NTOK + ks * 32 + g * 8;

    f32x4 o0 = {}, o1 = {};
    f32x4 lacc = {};
    float m_ = -1e30f;

    for (int step = 0; step < 64; ++step) {
        __syncthreads();                     // prev compute done: LDS overwritable
        *(uint4*)&KH[kr][kc] = sKH;          // waits on loads issued one step ago
        *(uint4*)&KL[kr][kc] = sKL;
        __syncthreads();                     // tile visible

        // issue THIS step's V fragment loads (consumed after QK^T + softmax)
        frag_u vh[2][2], vl[2][2];
        {
            const int vo = step * 64;
            #pragma unroll
            for (int mt = 0; mt < 2; ++mt)
                #pragma unroll
                for (int ks = 0; ks < 2; ++ks) {
                    vh[mt][ks].q = *(const uint4*)(Vhi + vbase[mt][ks] + vo);
                    vl[mt][ks].q = *(const uint4*)(Vlo + vbase[mt][ks] + vo);
                }
        }

        // issue next-step K loads (land during this step's compute)
        {
            const int nx = ((step + 1) & 63) * 64;   // wrap: valid, unused
            sKH = *(const uint4*)(Khi + kgbase + nx * HD);
            sKL = *(const uint4*)(Klo + kgbase + nx * HD);
        }

        // ---- K fragments from LDS ----
        bf16x8 kh[4], kl[4];
        #pragma unroll
        for (int t = 0; t < 4; ++t) {
            kh[t] = *(const bf16x8*)&KH[16 * t + lq][g * 8];
            kl[t] = *(const bf16x8*)&KL[16 * t + lq][g * 8];
        }

        // ---- QK^T (3-term split) ----
        f32x4 sc[4];
        #pragma unroll
        for (int t = 0; t < 4; ++t) {
            f32x4 cc = {0.f, 0.f, 0.f, 0.f};
            cc = __builtin_amdgcn_mfma_f32_16x16x32_bf16(kh[t], qh, cc, 0, 0, 0);
            cc = __builtin_amdgcn_mfma_f32_16x16x32_bf16(kh[t], ql, cc, 0, 0, 0);
            cc = __builtin_amdgcn_mfma_f32_16x16x32_bf16(kl[t], qh, cc, 0, 0, 0);
            sc[t] = cc;
        }

        // ---- online softmax ----
        float mx = fmaxf(
            fmaxf(fmaxf(fmaxf(sc[0][0], sc[0][1]), fmaxf(sc[0][2], sc[0][3])),
                  fmaxf(fmaxf(sc[1][0], sc[1][1]), fmaxf(sc[1][2], sc[1][3]))),
            fmaxf(fmaxf(fmaxf(sc[2][0], sc[2][1]), fmaxf(sc[2][2], sc[2][3])),
                  fmaxf(fmaxf(sc[3][0], sc[3][1]), fmaxf(sc[3][2], sc[3][3]))));
        mx = fmaxf(mx, __shfl_xor(mx, 16));
        mx = fmaxf(mx, __shfl_xor(mx, 32));
        mx = fmaxf(mx, m_);
        float rs = exp2_fast(m_ - mx);
        m_ = mx;
        lacc *= rs;
        o0 *= rs;
        o1 *= rs;

        unsigned ph[4][2];
        #pragma unroll
        for (int t = 0; t < 4; ++t) {
            float p0 = exp2_fast(sc[t][0] - mx);
            float p1 = exp2_fast(sc[t][1] - mx);
            float p2 = exp2_fast(sc[t][2] - mx);
            float p3 = exp2_fast(sc[t][3] - mx);
            lacc += (f32x4){p0, p1, p2, p3};
            ph[t][0] = cvt_pk_bf16(p0, p1);
            ph[t][1] = cvt_pk_bf16(p2, p3);
        }

        // ---- PV: redistribute P (C-frag -> B-frag), V frags from registers ----
        #pragma unroll
        for (int ks = 0; ks < 2; ++ks) {
            unsigned h00 = ph[2 * ks][0], h10 = ph[2 * ks + 1][0];
            unsigned h01 = ph[2 * ks][1], h11 = ph[2 * ks + 1][1];
            permlane_pv(h00, h10);
            permlane_pv(h01, h11);
            frag_u PH; PH.u = (u32x4){h00, h01, h10, h11};
            o0 = __builtin_amdgcn_mfma_f32_16x16x32_bf16(vh[0][ks].b, PH.b, o0, 0, 0, 0);
            o0 = __builtin_amdgcn_mfma_f32_16x16x32_bf16(vl[0][ks].b, PH.b, o0, 0, 0, 0);
            o1 = __builtin_amdgcn_mfma_f32_16x16x32_bf16(vh[1][ks].b, PH.b, o1, 0, 0, 0);
            o1 = __builtin_amdgcn_mfma_f32_16x16x32_bf16(vl[1][ks].b, PH.b, o1, 0, 0, 0);
        }
    }

    // ---- finalize: reduce l across g-groups, scale, store ----
    const int b_ = bh >> 3, h_ = bh & 7;
    float ls = (lacc[0] + lacc[1]) + (lacc[2] + lacc[3]);
    ls += __shfl_xor(ls, 16);
    ls += __shfl_xor(ls, 32);
    const float inv = 1.0f / ls;
    const int qg = q0 + lq;
    {
        float4 st;
        st.x = o0[0] * inv; st.y = o0[1] * inv;
        st.z = o0[2] * inv; st.w = o0[3] * inv;
        *(float4*)&AO[((size_t)b_ * NTOK + qg) * CDIM + h_ * 32 + g * 4] = st;
    }
    {
        float4 st;
        st.x = o1[0] * inv; st.y = o1[1] * inv;
        st.z = o1[2] * inv; st.w = o1[3] * inv;
        *(float4*)&AO[((size_t)b_ * NTOK + qg) * CDIM + h_ * 32 + 16 + g * 4] = st;
    }
}

// ---------------- Output projection GEMM (unchanged, working) ----------------
__global__ __launch_bounds__(256) void proj_gemm(
    const float* __restrict__ A, const float* __restrict__ W,
    const float* __restrict__ bias, float* __restrict__ out)
{
    __shared__ float As[BK][BM + 4];
    __shared__ float Bs[BK][BN + 4];

    const int tid = threadIdx.x;
    const int tx = tid & 15;
    const int ty = tid >> 4;
    const int row0 = blockIdx.x * BM;
    const int col0 = blockIdx.y * BN;

    float c[4][4] = {};

    for (int k0 = 0; k0 < CDIM; k0 += BK) {
        #pragma unroll
        for (int i = 0; i < 4; ++i) {
            int l = tid + i * 256;
            int r = l >> 4;
            int k4 = (l & 15) << 2;
            float4 v = *(const float4*)&A[(size_t)(row0 + r) * CDIM + k0 + k4];
            As[k4 + 0][r] = v.x; As[k4 + 1][r] = v.y;
            As[k4 + 2][r] = v.z; As[k4 + 3][r] = v.w;
        }
        #pragma unroll
        for (int i = 0; i < 4; ++i) {
            int l = tid + i * 256;
            int r = l >> 4;
            int c4 = (l & 15) << 2;
            *(float4*)&Bs[r][c4] = *(const float4*)&W[(size_t)(k0 + r) * CDIM + col0 + c4];
        }
        __syncthreads();

        #pragma unroll 16
        for (int kk = 0; kk < BK; ++kk) {
            float4 a = *(const float4*)&As[kk][ty << 2];
            float4 b = *(const float4*)&Bs[kk][tx << 2];
            float av[4] = {a.x, a.y, a.z, a.w};
            float bv[4] = {b.x, b.y, b.z, b.w};
            #pragma unroll
            for (int i = 0; i < 4; ++i)
                #pragma unroll
                for (int j = 0; j < 4; ++j)
                    c[i][j] = fmaf(av[i], bv[j], c[i][j]);
        }
        __syncthreads();
    }

    #pragma unroll
    for (int i = 0; i < 4; ++i) {
        int gr = row0 + (ty << 2) + i;
        #pragma unroll
        for (int j = 0; j < 4; ++j) {
            int gc = col0 + (tx << 2) + j;
            out[(size_t)gr * CDIM + gc] = c[i][j] + bias[gc];
        }
    }
}

extern "C" void kernel_launch(void* const* d_in, const int* in_sizes, int n_in,
                              void* d_out, int out_size, void* d_ws, size_t ws_size,
                              hipStream_t stream)
{
    const float* x      = (const float*)d_in[0];
    const float* w_qkv  = (const float*)d_in[1];
    const float* b_qkv  = (const float*)d_in[2];
    const float* w_proj = (const float*)d_in[3];
    const float* b_proj = (const float*)d_in[4];
    // d_in[5] rel_bias: per-head scalar over the full score matrix -> softmax no-op.

    float* out = (float*)d_out;

    // ws: Qhi|Qlo|Khi|Klo|Vhi|Vlo (4MB each, bf16) + AO (8MB f32) = 32MB
    const size_t NE = (size_t)BATCH * NH * NTOK * HD;   // 2,097,152
    char* p = (char*)d_ws;
    unsigned short* Qhi = (unsigned short*)p;  p += NE * 2;
    unsigned short* Qlo = (unsigned short*)p;  p += NE * 2;
    unsigned short* Khi = (unsigned short*)p;  p += NE * 2;
    unsigned short* Klo = (unsigned short*)p;  p += NE * 2;
    unsigned short* Vhi = (unsigned short*)p;  p += NE * 2;
    unsigned short* Vlo = (unsigned short*)p;  p += NE * 2;
    float* AO           = (float*)p;

    {
        dim3 grid(MROWS / BM, 768 / BN);   // 128 x 12
        qkv_gemm<<<grid, 256, 0, stream>>>(x, w_qkv, b_qkv, Qhi, Qlo, Khi, Klo, Vhi, Vlo);
    }
    {
        dim3 grid(1024);                   // 64 q-chunks x 16 bh (bh = bx & 15)
        attn_v9<<<grid, 256, 0, stream>>>(Qhi, Qlo, Khi, Klo, Vhi, Vlo, AO);
    }
    {
        dim3 grid(MROWS / BM, CDIM / BN);  // 128 x 4
        proj_gemm<<<grid, 256, 0, stream>>>(AO, w_proj, b_proj, out);
    }
}

// Round 10
// 151.933 us; speedup vs baseline: 2.1215x; 2.1215x over previous
//
#include <hip/hip_runtime.h>
#include <math.h>

#define BATCH 2
#define NTOK 4096        // H*W
#define CDIM 256
#define NH 8
#define HD 32
#define MROWS (BATCH * NTOK)   // 8192

typedef __attribute__((ext_vector_type(8))) short bf16x8;
typedef __attribute__((ext_vector_type(4))) float f32x4;
typedef __attribute__((ext_vector_type(4))) unsigned u32x4;
typedef unsigned short ushort_t;

union frag_u { uint4 q; u32x4 u; bf16x8 b; };

__device__ __forceinline__ unsigned short f2bf(float f) {
    union { float f; unsigned u; } x; x.f = f;
    unsigned r = x.u + 0x7FFFu + ((x.u >> 16) & 1u);   // RNE
    return (unsigned short)(r >> 16);
}
__device__ __forceinline__ float bf2f(unsigned short h) {
    union { unsigned u; float f; } x; x.u = ((unsigned)h) << 16; return x.f;
}
__device__ __forceinline__ float exp2_fast(float x) {
    float r;
    asm("v_exp_f32 %0, %1\n\ts_nop 0" : "=v"(r) : "v"(x));   // proven r2-r9
    return r;
}
__device__ __forceinline__ unsigned cvt_pk_bf16(float a, float b) {
    unsigned r;   // lo16 = bf16(a), hi16 = bf16(b), RNE
    asm("v_cvt_pk_bf16_f32 %0, %1, %2" : "=v"(r) : "v"(a), "v"(b));
    return r;
}
// C-frag dword pair (tile 2ks, tile 2ks+1) -> B-frag dword pair (w0, w1); proven r3-r9
__device__ __forceinline__ void permlane_pv(unsigned &a, unsigned &b) {
    asm("s_nop 1\n\t"
        "v_permlane32_swap_b32 %0, %1\n\t"
        "s_nop 1\n\t"
        "v_permlane16_swap_b32 %0, %1" : "+v"(a), "+v"(b));
}

// ---------------- prep: split fp32 -> bf16 hi/lo (X) ----------------
__global__ __launch_bounds__(256) void split_f32(
    const float* __restrict__ src, ushort_t* __restrict__ hi, ushort_t* __restrict__ lo)
{
    const int i = blockIdx.x * 256 + threadIdx.x;     // 4 floats per thread
    float4 v = *(const float4*)&src[i * 4];
    unsigned h01 = cvt_pk_bf16(v.x, v.y);
    unsigned h23 = cvt_pk_bf16(v.z, v.w);
    union { unsigned u; float f; } a, b;
    a.u = h01 << 16; b.u = h01 & 0xFFFF0000u;
    unsigned l01 = cvt_pk_bf16(v.x - a.f, v.y - b.f);
    a.u = h23 << 16; b.u = h23 & 0xFFFF0000u;
    unsigned l23 = cvt_pk_bf16(v.z - a.f, v.w - b.f);
    *(uint2*)&hi[i * 4] = make_uint2(h01, h23);
    *(uint2*)&lo[i * 4] = make_uint2(l01, l23);
}

// ---------------- prep: transpose + split W[K][N] -> Wt hi/lo [N][K] ----------------
__global__ __launch_bounds__(256) void prep_wt(
    const float* __restrict__ W, ushort_t* __restrict__ Whi, ushort_t* __restrict__ Wlo,
    int K, int N)
{
    __shared__ float T[32][33];
    const int tid = threadIdx.x;
    const int n0 = blockIdx.x * 32, k0 = blockIdx.y * 32;
    const int r = tid >> 3, c4 = (tid & 7) << 2;
    float4 v = *(const float4*)&W[(size_t)(k0 + r) * N + n0 + c4];
    T[r][c4 + 0] = v.x; T[r][c4 + 1] = v.y; T[r][c4 + 2] = v.z; T[r][c4 + 3] = v.w;
    __syncthreads();
    float f0 = T[c4 + 0][r], f1 = T[c4 + 1][r], f2 = T[c4 + 2][r], f3 = T[c4 + 3][r];
    unsigned h01 = cvt_pk_bf16(f0, f1), h23 = cvt_pk_bf16(f2, f3);
    union { unsigned u; float f; } a, b;
    a.u = h01 << 16; b.u = h01 & 0xFFFF0000u;
    unsigned l01 = cvt_pk_bf16(f0 - a.f, f1 - b.f);
    a.u = h23 << 16; b.u = h23 & 0xFFFF0000u;
    unsigned l23 = cvt_pk_bf16(f2 - a.f, f3 - b.f);
    size_t o = (size_t)(n0 + r) * K + k0 + c4;
    *(uint2*)&Whi[o] = make_uint2(h01, h23);
    *(uint2*)&Wlo[o] = make_uint2(l01, l23);
}

// ---------------- QKV projection: split-bf16 MFMA GEMM ----------------
// C = X(8192x256) * Wq(256x768); A/B staged hi/lo in LDS, 3-term MFMA.
// Operand convention identical to attn (proven): A-op lane->M-row=lq, k=g*8+j;
// B-op lane->N-col=lq; C: row=4g+reg (M), col=lq (N).
__global__ __launch_bounds__(256) void qkv_mfma(
    const ushort_t* __restrict__ Xhi, const ushort_t* __restrict__ Xlo,
    const ushort_t* __restrict__ Wthi, const ushort_t* __restrict__ Wtlo,  // [768][256]
    const float* __restrict__ bias,
    ushort_t* __restrict__ Qhi, ushort_t* __restrict__ Qlo,
    ushort_t* __restrict__ Khi, ushort_t* __restrict__ Klo,
    ushort_t* __restrict__ Vhi)
{
    __shared__ __align__(16) ushort_t Ah[64][40], Al[64][40], Bh[64][40], Bl[64][40];

    const int tid = threadIdx.x;
    const int w = tid >> 6, lane = tid & 63, lq = lane & 15, g = lane >> 4;
    const int wm = w >> 1, wn = w & 1;
    const int row0 = blockIdx.x * 64, col0 = blockIdx.y * 64;
    const int sr = tid >> 2, sc = (tid & 3) << 3;

    f32x4 acc[2][2] = {};

    for (int k0 = 0; k0 < CDIM; k0 += 32) {
        __syncthreads();
        *(uint4*)&Ah[sr][sc] = *(const uint4*)&Xhi[(size_t)(row0 + sr) * CDIM + k0 + sc];
        *(uint4*)&Al[sr][sc] = *(const uint4*)&Xlo[(size_t)(row0 + sr) * CDIM + k0 + sc];
        *(uint4*)&Bh[sr][sc] = *(const uint4*)&Wthi[(size_t)(col0 + sr) * CDIM + k0 + sc];
        *(uint4*)&Bl[sr][sc] = *(const uint4*)&Wtlo[(size_t)(col0 + sr) * CDIM + k0 + sc];
        __syncthreads();

        bf16x8 ah[2], al[2], bh[2], bl[2];
        #pragma unroll
        for (int i = 0; i < 2; ++i) {
            ah[i] = *(const bf16x8*)&Ah[wm * 32 + i * 16 + lq][g * 8];
            al[i] = *(const bf16x8*)&Al[wm * 32 + i * 16 + lq][g * 8];
        }
        #pragma unroll
        for (int j = 0; j < 2; ++j) {
            bh[j] = *(const bf16x8*)&Bh[wn * 32 + j * 16 + lq][g * 8];
            bl[j] = *(const bf16x8*)&Bl[wn * 32 + j * 16 + lq][g * 8];
        }
        #pragma unroll
        for (int i = 0; i < 2; ++i)
            #pragma unroll
            for (int j = 0; j < 2; ++j) {
                acc[i][j] = __builtin_amdgcn_mfma_f32_16x16x32_bf16(ah[i], bh[j], acc[i][j], 0, 0, 0);
                acc[i][j] = __builtin_amdgcn_mfma_f32_16x16x32_bf16(ah[i], bl[j], acc[i][j], 0, 0, 0);
                acc[i][j] = __builtin_amdgcn_mfma_f32_16x16x32_bf16(al[i], bh[j], acc[i][j], 0, 0, 0);
            }
    }

    // epilogue: bias + hi/lo split + scatter (Q scaled by QSC; V transposed, hi only)
    const int s = col0 >> 8;            // 0=Q 1=K 2=V (block-uniform)
    const int b_ = row0 >> 12;
    const int nb0 = (row0 & (NTOK - 1)) + wm * 32 + 4 * g;
    const float QSC = (float)(1.4426950408889634 / 5.656854249492381);

    #pragma unroll
    for (int j = 0; j < 2; ++j) {
        const int gcol = col0 + wn * 32 + j * 16 + lq;
        const float bv = bias[gcol];
        const int h = (gcol >> 5) & 7, e = gcol & 31;
        const int bh_ = b_ * NH + h;
        #pragma unroll
        for (int i = 0; i < 2; ++i) {
            #pragma unroll
            for (int r = 0; r < 4; ++r) {
                const int n = nb0 + i * 16 + r;
                float val = acc[i][j][r] + bv;
                if (s == 0) {
                    val *= QSC;
                    unsigned short hh = f2bf(val);
                    unsigned short ll = f2bf(val - bf2f(hh));
                    size_t idx = ((size_t)bh_ * NTOK + n) * HD + e;
                    Qhi[idx] = hh; Qlo[idx] = ll;
                } else if (s == 1) {
                    unsigned short hh = f2bf(val);
                    unsigned short ll = f2bf(val - bf2f(hh));
                    size_t idx = ((size_t)bh_ * NTOK + n) * HD + e;
                    Khi[idx] = hh; Klo[idx] = ll;
                } else {
                    Vhi[((size_t)bh_ * HD + e) * NTOK + n] = f2bf(val);
                }
            }
        }
    }
}

// ---------------- MFMA flash attention v10 ----------------
// v6 structure (K+V staged in LDS, 2 barriers/step, reg prefetch) with:
// V single-bf16 (half LDS traffic + half PV MFMAs), V pitch 68 (bank-balanced),
// defer-max rescale (skip unless !__all(mx <= m+8)), AO written as bf16 hi/lo.
__global__ __launch_bounds__(256, 3) void attn_v10(
    const ushort_t* __restrict__ Qhi, const ushort_t* __restrict__ Qlo,
    const ushort_t* __restrict__ Khi, const ushort_t* __restrict__ Klo,
    const ushort_t* __restrict__ Vhi,
    ushort_t* __restrict__ AOhi, ushort_t* __restrict__ AOlo)
{
    __shared__ __align__(16) ushort_t KH[64][44], KL[64][44];   // pitch 88B
    __shared__ __align__(16) ushort_t VH[32][68];               // pitch 136B

    const int tid = threadIdx.x;
    const int w = tid >> 6, lane = tid & 63, lq = lane & 15, g = lane >> 4;
    const int bx = blockIdx.x;
    const int bh = bx & 15, qc = bx >> 4;     // same-head blocks share XCD L2
    const int q0 = qc * 64 + w * 16;
    const int kb = bh * (NTOK * HD);
    const int vb = bh * (HD * NTOK);

    // Q fragment (pre-scaled by scale*log2e in qkv epilogue)
    bf16x8 qh, ql;
    {
        const int qi = kb + (q0 + lq) * HD + g * 8;
        qh = *(const bf16x8*)(Qhi + qi);
        ql = *(const bf16x8*)(Qlo + qi);
    }

    // staging slots
    const int kr = tid >> 2, kc = (tid & 3) << 3;
    const int vr = tid >> 3, vc = (tid & 7) << 3;
    const int kgbase = kb + kr * HD + kc;
    const int vgbase = vb + vr * NTOK + vc;

    uint4 sKH = *(const uint4*)(Khi + kgbase);
    uint4 sKL = *(const uint4*)(Klo + kgbase);
    uint4 sVH = *(const uint4*)(Vhi + vgbase);

    f32x4 o0 = {}, o1 = {};
    f32x4 lacc = {};
    float m_ = -1e30f;

    for (int step = 0; step < 64; ++step) {
        __syncthreads();
        *(uint4*)&KH[kr][kc] = sKH;
        *(uint4*)&KL[kr][kc] = sKL;
        *(uint4*)&VH[vr][vc] = sVH;
        __syncthreads();

        {
            const int nx = ((step + 1) & 63) * 64;
            sKH = *(const uint4*)(Khi + kgbase + nx * HD);
            sKL = *(const uint4*)(Klo + kgbase + nx * HD);
            sVH = *(const uint4*)(Vhi + vgbase + nx);
        }

        bf16x8 kh[4], kl[4];
        #pragma unroll
        for (int t = 0; t < 4; ++t) {
            kh[t] = *(const bf16x8*)&KH[16 * t + lq][g * 8];
            kl[t] = *(const bf16x8*)&KL[16 * t + lq][g * 8];
        }

        f32x4 sc[4];
        #pragma unroll
        for (int t = 0; t < 4; ++t) {
            f32x4 cc = {0.f, 0.f, 0.f, 0.f};
            cc = __builtin_amdgcn_mfma_f32_16x16x32_bf16(kh[t], qh, cc, 0, 0, 0);
            cc = __builtin_amdgcn_mfma_f32_16x16x32_bf16(kh[t], ql, cc, 0, 0, 0);
            cc = __builtin_amdgcn_mfma_f32_16x16x32_bf16(kl[t], qh, cc, 0, 0, 0);
            sc[t] = cc;
        }

        float mx = fmaxf(
            fmaxf(fmaxf(fmaxf(sc[0][0], sc[0][1]), fmaxf(sc[0][2], sc[0][3])),
                  fmaxf(fmaxf(sc[1][0], sc[1][1]), fmaxf(sc[1][2], sc[1][3]))),
            fmaxf(fmaxf(fmaxf(sc[2][0], sc[2][1]), fmaxf(sc[2][2], sc[2][3])),
                  fmaxf(fmaxf(sc[3][0], sc[3][1]), fmaxf(sc[3][2], sc[3][3]))));
        mx = fmaxf(mx, __shfl_xor(mx, 16));
        mx = fmaxf(mx, __shfl_xor(mx, 32));

        // defer-max: rescale only when the bound would be violated (rare)
        if (!__all(mx <= m_ + 8.0f)) {
            float mnew = fmaxf(m_, mx);
            float rs = exp2_fast(m_ - mnew);
            m_ = mnew;
            lacc *= rs;
            o0 *= rs;
            o1 *= rs;
        }

        unsigned ph[4][2];
        #pragma unroll
        for (int t = 0; t < 4; ++t) {
            float p0 = exp2_fast(sc[t][0] - m_);
            float p1 = exp2_fast(sc[t][1] - m_);
            float p2 = exp2_fast(sc[t][2] - m_);
            float p3 = exp2_fast(sc[t][3] - m_);
            lacc += (f32x4){p0, p1, p2, p3};
            ph[t][0] = cvt_pk_bf16(p0, p1);
            ph[t][1] = cvt_pk_bf16(p2, p3);
        }

        #pragma unroll
        for (int ks = 0; ks < 2; ++ks) {
            unsigned h00 = ph[2 * ks][0], h10 = ph[2 * ks + 1][0];
            unsigned h01 = ph[2 * ks][1], h11 = ph[2 * ks + 1][1];
            permlane_pv(h00, h10);
            permlane_pv(h01, h11);
            frag_u PH; PH.u = (u32x4){h00, h01, h10, h11};
            {
                bf16x8 vhf = *(const bf16x8*)&VH[lq][ks * 32 + g * 8];
                o0 = __builtin_amdgcn_mfma_f32_16x16x32_bf16(vhf, PH.b, o0, 0, 0, 0);
            }
            {
                bf16x8 vhf = *(const bf16x8*)&VH[16 + lq][ks * 32 + g * 8];
                o1 = __builtin_amdgcn_mfma_f32_16x16x32_bf16(vhf, PH.b, o1, 0, 0, 0);
            }
        }
    }

    // finalize: reduce l across g-groups, normalize, write AO as bf16 hi/lo
    const int b_ = bh >> 3, h_ = bh & 7;
    float ls = (lacc[0] + lacc[1]) + (lacc[2] + lacc[3]);
    ls += __shfl_xor(ls, 16);
    ls += __shfl_xor(ls, 32);
    const float inv = 1.0f / ls;
    const int qg = q0 + lq;
    const size_t obase = ((size_t)b_ * NTOK + qg) * CDIM + h_ * 32 + g * 4;
    #pragma unroll
    for (int mt = 0; mt < 2; ++mt) {
        f32x4 ov = (mt == 0) ? o0 : o1;
        float v0 = ov[0] * inv, v1 = ov[1] * inv, v2 = ov[2] * inv, v3 = ov[3] * inv;
        unsigned h01 = cvt_pk_bf16(v0, v1), h23 = cvt_pk_bf16(v2, v3);
        union { unsigned u; float f; } a, b;
        a.u = h01 << 16; b.u = h01 & 0xFFFF0000u;
        unsigned l01 = cvt_pk_bf16(v0 - a.f, v1 - b.f);
        a.u = h23 << 16; b.u = h23 & 0xFFFF0000u;
        unsigned l23 = cvt_pk_bf16(v2 - a.f, v3 - b.f);
        *(uint2*)&AOhi[obase + mt * 16] = make_uint2(h01, h23);
        *(uint2*)&AOlo[obase + mt * 16] = make_uint2(l01, l23);
    }
}

// ---------------- Output projection: split-bf16 MFMA GEMM ----------------
__global__ __launch_bounds__(256) void proj_mfma(
    const ushort_t* __restrict__ AOhi, const ushort_t* __restrict__ AOlo,
    const ushort_t* __restrict__ Wthi, const ushort_t* __restrict__ Wtlo,  // [256][256]
    const float* __restrict__ bias, float* __restrict__ out)
{
    __shared__ __align__(16) ushort_t Ah[64][40], Al[64][40], Bh[64][40], Bl[64][40];

    const int tid = threadIdx.x;
    const int w = tid >> 6, lane = tid & 63, lq = lane & 15, g = lane >> 4;
    const int wm = w >> 1, wn = w & 1;
    const int row0 = blockIdx.x * 64, col0 = blockIdx.y * 64;
    const int sr = tid >> 2, sc = (tid & 3) << 3;

    f32x4 acc[2][2] = {};

    for (int k0 = 0; k0 < CDIM; k0 += 32) {
        __syncthreads();
        *(uint4*)&Ah[sr][sc] = *(const uint4*)&AOhi[(size_t)(row0 + sr) * CDIM + k0 + sc];
        *(uint4*)&Al[sr][sc] = *(const uint4*)&AOlo[(size_t)(row0 + sr) * CDIM + k0 + sc];
        *(uint4*)&Bh[sr][sc] = *(const uint4*)&Wthi[(size_t)(col0 + sr) * CDIM + k0 + sc];
        *(uint4*)&Bl[sr][sc] = *(const uint4*)&Wtlo[(size_t)(col0 + sr) * CDIM + k0 + sc];
        __syncthreads();

        bf16x8 ah[2], al[2], bh[2], bl[2];
        #pragma unroll
        for (int i = 0; i < 2; ++i) {
            ah[i] = *(const bf16x8*)&Ah[wm * 32 + i * 16 + lq][g * 8];
            al[i] = *(const bf16x8*)&Al[wm * 32 + i * 16 + lq][g * 8];
        }
        #pragma unroll
        for (int j = 0; j < 2; ++j) {
            bh[j] = *(const bf16x8*)&Bh[wn * 32 + j * 16 + lq][g * 8];
            bl[j] = *(const bf16x8*)&Bl[wn * 32 + j * 16 + lq][g * 8];
        }
        #pragma unroll
        for (int i = 0; i < 2; ++i)
            #pragma unroll
            for (int j = 0; j < 2; ++j) {
                acc[i][j] = __builtin_amdgcn_mfma_f32_16x16x32_bf16(ah[i], bh[j], acc[i][j], 0, 0, 0);
                acc[i][j] = __builtin_amdgcn_mfma_f32_16x16x32_bf16(ah[i], bl[j], acc[i][j], 0, 0, 0);
                acc[i][j] = __builtin_amdgcn_mfma_f32_16x16x32_bf16(al[i], bh[j], acc[i][j], 0, 0, 0);
            }
    }

    #pragma unroll
    for (int j = 0; j < 2; ++j) {
        const int gcol = col0 + wn * 32 + j * 16 + lq;
        const float bv = bias[gcol];
        #pragma unroll
        for (int i = 0; i < 2; ++i) {
            #pragma unroll
            for (int r = 0; r < 4; ++r) {
                const int grow = row0 + wm * 32 + i * 16 + 4 * g + r;
                out[(size_t)grow * CDIM + gcol] = acc[i][j][r] + bv;
            }
        }
    }
}

extern "C" void kernel_launch(void* const* d_in, const int* in_sizes, int n_in,
                              void* d_out, int out_size, void* d_ws, size_t ws_size,
                              hipStream_t stream)
{
    const float* x      = (const float*)d_in[0];
    const float* w_qkv  = (const float*)d_in[1];
    const float* b_qkv  = (const float*)d_in[2];
    const float* w_proj = (const float*)d_in[3];
    const float* b_proj = (const float*)d_in[4];
    // d_in[5] rel_bias: per-head scalar over the full score matrix -> softmax no-op.

    float* out = (float*)d_out;

    // ws layout (29MB total):
    //  R1 (8MB): Xhi/Xlo, later reused as AOhi/AOlo (X dead after qkv_mfma)
    //  weights (1MB): Wqt hi/lo [768][256], Wpt hi/lo [256][256]
    //  Qhi Qlo Khi Klo Vhi (4MB each = 20MB)
    const size_t NE = (size_t)BATCH * NH * NTOK * HD;   // 2,097,152
    char* p = (char*)d_ws;
    ushort_t* Xhi   = (ushort_t*)p;                    // also AOhi
    ushort_t* Xlo   = (ushort_t*)(p + 4194304);        // also AOlo
    ushort_t* Wqthi = (ushort_t*)(p + 8388608);
    ushort_t* Wqtlo = (ushort_t*)(p + 8388608 + 393216);
    ushort_t* Wpthi = (ushort_t*)(p + 8388608 + 786432);
    ushort_t* Wptlo = (ushort_t*)(p + 8388608 + 917504);
    char* q = p + 8388608 + 1048576;                   // 9MB
    ushort_t* Qhi = (ushort_t*)q;
    ushort_t* Qlo = (ushort_t*)(q + 4194304);
    ushort_t* Khi = (ushort_t*)(q + 8388608);
    ushort_t* Klo = (ushort_t*)(q + 12582912);
    ushort_t* Vhi = (ushort_t*)(q + 16777216);
    ushort_t* AOhi = Xhi;
    ushort_t* AOlo = Xlo;

    // 0) prep: split X; transpose+split weights
    split_f32<<<2048, 256, 0, stream>>>(x, Xhi, Xlo);                 // 2M floats
    prep_wt<<<dim3(24, 8), 256, 0, stream>>>(w_qkv, Wqthi, Wqtlo, 256, 768);
    prep_wt<<<dim3(8, 8), 256, 0, stream>>>(w_proj, Wpthi, Wptlo, 256, 256);

    // 1) QKV projection (MFMA)
    qkv_mfma<<<dim3(MROWS / 64, 768 / 64), 256, 0, stream>>>(
        Xhi, Xlo, Wqthi, Wqtlo, b_qkv, Qhi, Qlo, Khi, Klo, Vhi);

    // 2) attention
    attn_v10<<<1024, 256, 0, stream>>>(Qhi, Qlo, Khi, Klo, Vhi, AOhi, AOlo);

    // 3) output projection (MFMA)
    proj_mfma<<<dim3(MROWS / 64, CDIM / 64), 256, 0, stream>>>(
        AOhi, AOlo, Wpthi, Wptlo, b_proj, out);
}